// Round 1
// baseline (1578.040 us; speedup 1.0000x reference)
//
#include <hip/hip_runtime.h>
#include <cstddef>

#define B_    256
#define SX_   256
#define SY_   70
#define F_    512
#define EMB_  256
#define NY_   (B_*SY_)     // 17920
#define NE_   (4*B_*SY_)   // 71680

// ---------------------------------------------------------------------------
// Flat NN GEMM: C[M,N] = A[M,K] @ B[K,N] (+bias). M%64==0, N%64==0, K%16==0.
// 64x64 tile, 256 threads, 4x4 microtile.
// ---------------------------------------------------------------------------
__global__ __launch_bounds__(256)
void gemm_nn(const float* __restrict__ A, const float* __restrict__ B,
             float* __restrict__ C, const float* __restrict__ bias,
             int M, int N, int K)
{
    __shared__ float As[16][68];   // [k][m], padded (272B rows, 16B aligned)
    __shared__ float Bs[16][64];   // [k][n]
    const int tid = threadIdx.x;
    const int tx = tid & 15, ty = tid >> 4;
    const int bm = blockIdx.y * 64, bn = blockIdx.x * 64;
    const int lr = tid >> 2;            // 0..63
    const int lk = (tid & 3) << 2;      // 0,4,8,12
    const int br = tid >> 4;            // 0..15
    const int bc = (tid & 15) << 2;     // 0..60

    float acc[4][4] = {};
    for (int k0 = 0; k0 < K; k0 += 16) {
        float4 a4 = *(const float4*)(A + (size_t)(bm + lr) * K + k0 + lk);
        As[lk+0][lr] = a4.x; As[lk+1][lr] = a4.y;
        As[lk+2][lr] = a4.z; As[lk+3][lr] = a4.w;
        float4 b4 = *(const float4*)(B + (size_t)(k0 + br) * N + bn + bc);
        *(float4*)&Bs[br][bc] = b4;
        __syncthreads();
#pragma unroll
        for (int k = 0; k < 16; ++k) {
            float4 av = *(const float4*)&As[k][ty << 2];
            float4 bv = *(const float4*)&Bs[k][tx << 2];
            float ar[4] = {av.x, av.y, av.z, av.w};
            float brr[4] = {bv.x, bv.y, bv.z, bv.w};
#pragma unroll
            for (int i = 0; i < 4; ++i)
#pragma unroll
                for (int j = 0; j < 4; ++j)
                    acc[i][j] = fmaf(ar[i], brr[j], acc[i][j]);
        }
        __syncthreads();
    }
    float4 bb = make_float4(0.f, 0.f, 0.f, 0.f);
    if (bias) bb = *(const float4*)(bias + bn + (tx << 2));
#pragma unroll
    for (int i = 0; i < 4; ++i) {
        float4 o;
        o.x = acc[i][0] + bb.x; o.y = acc[i][1] + bb.y;
        o.z = acc[i][2] + bb.z; o.w = acc[i][3] + bb.w;
        *(float4*)(C + (size_t)(bm + (ty << 2) + i) * N + bn + (tx << 2)) = o;
    }
}

// ---------------------------------------------------------------------------
// Batched NT GEMM (attention logits):
// L[b,i,j] = scale * sum_k Q[b*SY+i, k] * X[b*SX+j, k],  K=F_=512
// ---------------------------------------------------------------------------
__global__ __launch_bounds__(256)
void attn_logits(const float* __restrict__ Q, const float* __restrict__ X,
                 float* __restrict__ L)
{
    const int b = blockIdx.z;
    const float* A  = Q + (size_t)b * SY_ * F_;
    const float* Bx = X + (size_t)b * SX_ * F_;
    float* C = L + (size_t)b * SY_ * SX_;
    __shared__ float As[16][68];
    __shared__ float Bs[16][68];
    const int tid = threadIdx.x;
    const int tx = tid & 15, ty = tid >> 4;
    const int bm = blockIdx.y * 64, bn = blockIdx.x * 64;
    const int lr = tid >> 2;
    const int lk = (tid & 3) << 2;

    float acc[4][4] = {};
    for (int k0 = 0; k0 < F_; k0 += 16) {
        const int ar = bm + lr;
        float4 a4 = make_float4(0.f, 0.f, 0.f, 0.f);
        if (ar < SY_) a4 = *(const float4*)(A + (size_t)ar * F_ + k0 + lk);
        As[lk+0][lr] = a4.x; As[lk+1][lr] = a4.y;
        As[lk+2][lr] = a4.z; As[lk+3][lr] = a4.w;
        float4 b4 = *(const float4*)(Bx + (size_t)(bn + lr) * F_ + k0 + lk);
        Bs[lk+0][lr] = b4.x; Bs[lk+1][lr] = b4.y;
        Bs[lk+2][lr] = b4.z; Bs[lk+3][lr] = b4.w;
        __syncthreads();
#pragma unroll
        for (int k = 0; k < 16; ++k) {
            float4 av = *(const float4*)&As[k][ty << 2];
            float4 bv = *(const float4*)&Bs[k][tx << 2];
            float ar4[4] = {av.x, av.y, av.z, av.w};
            float br4[4] = {bv.x, bv.y, bv.z, bv.w};
#pragma unroll
            for (int i = 0; i < 4; ++i)
#pragma unroll
                for (int j = 0; j < 4; ++j)
                    acc[i][j] = fmaf(ar4[i], br4[j], acc[i][j]);
        }
        __syncthreads();
    }
    const float scale = 0.044194173824159216f;  // 1/sqrt(512)
#pragma unroll
    for (int i = 0; i < 4; ++i) {
        const int row = bm + (ty << 2) + i;
        if (row < SY_) {
            float4 o;
            o.x = acc[i][0] * scale; o.y = acc[i][1] * scale;
            o.z = acc[i][2] * scale; o.w = acc[i][3] * scale;
            *(float4*)(C + (size_t)row * SX_ + bn + (tx << 2)) = o;
        }
    }
}

// ---------------------------------------------------------------------------
// Row softmax over 256 entries, one wave per row, in place.
// ---------------------------------------------------------------------------
__global__ __launch_bounds__(256)
void softmax_rows(float* __restrict__ L, int rows)
{
    const int wave = (int)((blockIdx.x * (size_t)blockDim.x + threadIdx.x) >> 6);
    const int lane = threadIdx.x & 63;
    if (wave >= rows) return;
    float* row = L + (size_t)wave * 256;
    float4 v = *(const float4*)(row + (lane << 2));
    float m = fmaxf(fmaxf(v.x, v.y), fmaxf(v.z, v.w));
#pragma unroll
    for (int o = 32; o > 0; o >>= 1) m = fmaxf(m, __shfl_xor(m, o));
    v.x = __expf(v.x - m); v.y = __expf(v.y - m);
    v.z = __expf(v.z - m); v.w = __expf(v.w - m);
    float s = v.x + v.y + v.z + v.w;
#pragma unroll
    for (int o = 32; o > 0; o >>= 1) s += __shfl_xor(s, o);
    const float inv = 1.0f / s;
    v.x *= inv; v.y *= inv; v.z *= inv; v.w *= inv;
    *(float4*)(row + (lane << 2)) = v;
}

// ---------------------------------------------------------------------------
// Batched NN GEMM (attention context):
// CtxF[b,i,f] = sum_k Alpha[b,i,k] * X[b*SX+k, f],  K=SX_=256, N=F_=512
// ---------------------------------------------------------------------------
__global__ __launch_bounds__(256)
void attn_ctx(const float* __restrict__ Alpha, const float* __restrict__ X,
              float* __restrict__ CtxF)
{
    const int b = blockIdx.z;
    const float* A  = Alpha + (size_t)b * SY_ * SX_;
    const float* Bx = X + (size_t)b * SX_ * F_;
    float* C = CtxF + (size_t)b * SY_ * F_;
    __shared__ float As[16][68];
    __shared__ float Bs[16][64];
    const int tid = threadIdx.x;
    const int tx = tid & 15, ty = tid >> 4;
    const int bm = blockIdx.y * 64, bn = blockIdx.x * 64;
    const int lr = tid >> 2;
    const int lk = (tid & 3) << 2;
    const int br = tid >> 4;
    const int bc = (tid & 15) << 2;

    float acc[4][4] = {};
    for (int k0 = 0; k0 < SX_; k0 += 16) {
        const int ar = bm + lr;
        float4 a4 = make_float4(0.f, 0.f, 0.f, 0.f);
        if (ar < SY_) a4 = *(const float4*)(A + (size_t)ar * SX_ + k0 + lk);
        As[lk+0][lr] = a4.x; As[lk+1][lr] = a4.y;
        As[lk+2][lr] = a4.z; As[lk+3][lr] = a4.w;
        float4 b4 = *(const float4*)(Bx + (size_t)(k0 + br) * F_ + bn + bc);
        *(float4*)&Bs[br][bc] = b4;
        __syncthreads();
#pragma unroll
        for (int k = 0; k < 16; ++k) {
            float4 av = *(const float4*)&As[k][ty << 2];
            float4 bv = *(const float4*)&Bs[k][tx << 2];
            float ar4[4] = {av.x, av.y, av.z, av.w};
            float br4[4] = {bv.x, bv.y, bv.z, bv.w};
#pragma unroll
            for (int i = 0; i < 4; ++i)
#pragma unroll
                for (int j = 0; j < 4; ++j)
                    acc[i][j] = fmaf(ar4[i], br4[j], acc[i][j]);
        }
        __syncthreads();
    }
#pragma unroll
    for (int i = 0; i < 4; ++i) {
        const int row = bm + (ty << 2) + i;
        if (row < SY_) {
            float4 o;
            o.x = acc[i][0]; o.y = acc[i][1]; o.z = acc[i][2]; o.w = acc[i][3];
            *(float4*)(C + (size_t)row * F_ + bn + (tx << 2)) = o;
        }
    }
}

// ---------------------------------------------------------------------------
// y0 = embeds[tgt_y]
// ---------------------------------------------------------------------------
__global__ __launch_bounds__(64)
void gather_embed(const float* __restrict__ embeds, const int* __restrict__ tgt_y,
                  float* __restrict__ y)
{
    const int i = blockIdx.x;
    const int c = threadIdx.x << 2;
    const int v = tgt_y[i];
    *(float4*)(y + (size_t)i * EMB_ + c) =
        *(const float4*)(embeds + (size_t)v * EMB_ + c);
}

// ---------------------------------------------------------------------------
// agg[tgt[e],:] += h[src[e],:] + Ee[etype[e],:]
// ---------------------------------------------------------------------------
__global__ __launch_bounds__(256)
void scatter_edges(const float* __restrict__ h, const float* __restrict__ Ee,
                   const int* __restrict__ src, const int* __restrict__ tgt,
                   const int* __restrict__ etype, float* __restrict__ agg)
{
    const int e = blockIdx.x;
    const int c = threadIdx.x;
    const int s = src[e], t = tgt[e], ty = etype[e];
    const float val = h[(size_t)s * 256 + c] + Ee[(size_t)ty * 256 + c];
    atomicAdd(&agg[(size_t)t * 256 + c], val);
}

// ---------------------------------------------------------------------------
// y_next = relu(h + agg + ctx), float4
// ---------------------------------------------------------------------------
__global__ __launch_bounds__(256)
void relu_sum(const float* __restrict__ h, const float* __restrict__ agg,
              const float* __restrict__ ctx, float* __restrict__ out, int n4)
{
    const int i = blockIdx.x * 256 + threadIdx.x;
    if (i >= n4) return;
    float4 a = ((const float4*)h)[i];
    float4 b = ((const float4*)agg)[i];
    float4 c = ((const float4*)ctx)[i];
    float4 o;
    o.x = fmaxf(0.f, a.x + b.x + c.x);
    o.y = fmaxf(0.f, a.y + b.y + c.y);
    o.z = fmaxf(0.f, a.z + b.z + c.z);
    o.w = fmaxf(0.f, a.w + b.w + c.w);
    ((float4*)out)[i] = o;
}

// ---------------------------------------------------------------------------
// y_edge_rel_score[e,j] = concat(y[src[e]], y[tgt[e]]) . W[:,j] + b[j]
// ---------------------------------------------------------------------------
__global__ __launch_bounds__(256)
void edge_score(const float* __restrict__ y, const int* __restrict__ src,
                const int* __restrict__ tgt, const float* __restrict__ W,
                const float* __restrict__ bias, float* __restrict__ out)
{
    const int t = blockIdx.x * 256 + threadIdx.x;
    const int e = t >> 3, j = t & 7;
    if (e >= NE_) return;
    const float* ys = y + (size_t)src[e] * 256;
    const float* yt = y + (size_t)tgt[e] * 256;
    float acc = bias[j];
    for (int c = 0; c < 256; ++c) acc = fmaf(ys[c], W[c * 8 + j], acc);
    for (int c = 0; c < 256; ++c) acc = fmaf(yt[c], W[(256 + c) * 8 + j], acc);
    out[(size_t)e * 8 + j] = acc;
}

// ---------------------------------------------------------------------------
extern "C" void kernel_launch(void* const* d_in, const int* in_sizes, int n_in,
                              void* d_out, int out_size, void* d_ws, size_t ws_size,
                              hipStream_t stream)
{
    const float* x       = (const float*)d_in[0];
    const int*   tgt_y   = (const int*)d_in[2];
    const int*   eidx    = (const int*)d_in[3];
    const int*   etype   = (const int*)d_in[4];
    const float* embeds  = (const float*)d_in[6];
    const float* W_in[3] = {(const float*)d_in[7],  (const float*)d_in[11], (const float*)d_in[15]};
    const float* Wq[3]   = {(const float*)d_in[8],  (const float*)d_in[12], (const float*)d_in[16]};
    const float* Wv[3]   = {(const float*)d_in[9],  (const float*)d_in[13], (const float*)d_in[17]};
    const float* Ee[3]   = {(const float*)d_in[10], (const float*)d_in[14], (const float*)d_in[18]};
    const float* lin_z_w = (const float*)d_in[19];
    const float* lin_z_b = (const float*)d_in[20];
    const float* lin_g_w = (const float*)d_in[21];
    const float* lin_g_b = (const float*)d_in[22];
    const int* src = eidx;          // tgt_edge_index[0]
    const int* tgt = eidx + NE_;    // tgt_edge_index[1]

    float* out = (float*)d_out;
    float* ws  = (float*)d_ws;
    // d_out layout (floats)
    float* y_final = out;                       // [17920,256]
    float* score   = out + 4587520;             // [17920,256]
    float* esc     = out + 9175040;             // [71680,8]
    float* aout[3] = {out + 9748480, out + 14336000, out + 18923520};
    // workspace layout (floats)
    float* y_in = ws;                // [17920,256]
    float* h    = ws + 4587520;      // [17920,256]
    float* agg  = ws + 9175040;      // [17920,256]
    float* q    = ws + 13762560;     // [17920,512]
    float* ctxF = ws + 22937600;     // [B,SY,512]
    float* ctx  = ws + 32112640;     // [17920,256]

    gather_embed<<<NY_, 64, 0, stream>>>(embeds, tgt_y, y_in);

    const float* ycur = y_in;
    for (int l = 0; l < 3; ++l) {
        // h = y @ W_in
        gemm_nn<<<dim3(4, 280), 256, 0, stream>>>(ycur, W_in[l], h, nullptr, NY_, 256, 256);
        // agg = segment_sum(h[src] + Ee[etype], tgt)
        hipMemsetAsync(agg, 0, (size_t)NY_ * 256 * sizeof(float), stream);
        scatter_edges<<<NE_, 256, 0, stream>>>(h, Ee[l], src, tgt, etype, agg);
        // q = h @ Wq
        gemm_nn<<<dim3(8, 280), 256, 0, stream>>>(h, Wq[l], q, nullptr, NY_, 512, 256);
        // logits -> alpha (in d_out)
        attn_logits<<<dim3(4, 2, B_), 256, 0, stream>>>(q, x, aout[l]);
        softmax_rows<<<4480, 256, 0, stream>>>(aout[l], NY_);
        // ctxF = alpha @ x_b
        attn_ctx<<<dim3(8, 2, B_), 256, 0, stream>>>(aout[l], x, ctxF);
        // ctx = ctxF @ Wv
        gemm_nn<<<dim3(4, 280), 256, 0, stream>>>(ctxF, Wv[l], ctx, nullptr, NY_, 256, 512);
        // y_next = relu(h + agg + ctx)
        float* ynext = (l == 2) ? y_final : y_in;
        relu_sum<<<4480, 256, 0, stream>>>(h, agg, ctx, ynext, NY_ * 256 / 4);
        ycur = ynext;
    }
    // y_score = y @ lin_z_w + lin_z_b
    gemm_nn<<<dim3(4, 280), 256, 0, stream>>>(y_final, lin_z_w, score, lin_z_b, NY_, 256, 256);
    // edge relation scores
    edge_score<<<2240, 256, 0, stream>>>(y_final, src, tgt, lin_g_w, lin_g_b, esc);
}

// Round 3
// 713.550 us; speedup vs baseline: 2.2115x; 2.2115x over previous
//
#include <hip/hip_runtime.h>
#include <cstddef>
#include <cstdint>

#define B_    256
#define SX_   256
#define SY_   70
#define F_    512
#define EMB_  256
#define NY_   (B_*SY_)     // 17920
#define NE_   (4*B_*SY_)   // 71680

typedef short s16x8 __attribute__((ext_vector_type(8)));   // MFMA A/B frag (8 bf16)
typedef float f32x4 __attribute__((ext_vector_type(4)));   // MFMA C/D frag
typedef unsigned short us4 __attribute__((ext_vector_type(4)));
typedef unsigned short us8 __attribute__((ext_vector_type(8)));

__device__ __forceinline__ unsigned short f2bf(float f) {
    unsigned u = __builtin_bit_cast(unsigned, f);
    u += 0x7fffu + ((u >> 16) & 1u);          // RNE
    return (unsigned short)(u >> 16);
}

// ---------------------------------------------------------------------------
// Unified bf16 MFMA GEMM, C = A @ Bt^T. A:[M][K] bf16, Bt:[N][K] bf16.
// 128x128 tile, BK=64, 4 waves (2x2 of 64x64), 16x16x32 MFMA.
// LDS tiles XOR-slot-swizzled; staged via global_load_lds with pre-swizzled
// global source (TB=0) or reg-staged transpose from [K][N] layout (TB=1).
// EPI: 0 = plain (scale, optional f32 + bf16 stores)
//      3 = relu(acc + aux1 + aux2) (ctx+relu fusion)
//      4 = acc + aux1[col] (bias)
// blockIdx.z = batch; sXb are per-batch element strides.
// ---------------------------------------------------------------------------
template<int EPI, int TB>
__global__ __launch_bounds__(256, 2)
void gemm_mfma(const unsigned short* __restrict__ A, int lda, long sAb,
               const unsigned short* __restrict__ Bt, int ldb, long sBb,
               float* __restrict__ Cf, int ldc, long sCfb,
               unsigned short* __restrict__ Cb, int ldcb, long sCbb,
               const float* __restrict__ aux1, const float* __restrict__ aux2,
               int M, int K, float scale)
{
    __shared__ unsigned short As[128 * 64];
    __shared__ unsigned short Bs[128 * 64];
    char* AsB = (char*)As;
    char* BsB = (char*)Bs;
    const int tid = threadIdx.x;
    const int z = blockIdx.z;
    A  += (size_t)z * sAb;
    Bt += (size_t)z * sBb;
    const int bm = blockIdx.y * 128, bn = blockIdx.x * 128;
    const int lane = tid & 63;
    const int w = tid >> 6, wr = w >> 1, wc = w & 1;
    const int l15 = lane & 15, lq = lane >> 4;

    f32x4 acc[4][4];
    const f32x4 z4 = {0.f, 0.f, 0.f, 0.f};
#pragma unroll
    for (int m = 0; m < 4; ++m)
#pragma unroll
        for (int n = 0; n < 4; ++n) acc[m][n] = z4;

    for (int k0 = 0; k0 < K; k0 += 64) {
        // ---- stage A tile [128 rows][64 k] ----
#pragma unroll
        for (int i = 0; i < 4; ++i) {
            const int row = i * 32 + (tid >> 3);
            const int k8  = (tid & 7) ^ (row & 7);
            int ra = bm + row; ra = (ra < M) ? ra : (M - 1);
            const unsigned short* g = A + (size_t)ra * lda + k0 + k8 * 8;
            __builtin_amdgcn_global_load_lds(
                (const __attribute__((address_space(1))) unsigned int*)g,
                (__attribute__((address_space(3))) unsigned int*)(AsB + i * 4096 + tid * 16),
                16, 0, 0);
        }
        if (TB == 0) {
            // ---- stage B tile [128 cols][64 k] from Bt[N][K] ----
#pragma unroll
            for (int i = 0; i < 4; ++i) {
                const int row = i * 32 + (tid >> 3);
                const int k8  = (tid & 7) ^ (row & 7);
                const unsigned short* g = Bt + (size_t)(bn + row) * ldb + k0 + k8 * 8;
                __builtin_amdgcn_global_load_lds(
                    (const __attribute__((address_space(1))) unsigned int*)g,
                    (__attribute__((address_space(3))) unsigned int*)(BsB + i * 4096 + tid * 16),
                    16, 0, 0);
            }
        } else {
            // ---- stage B tile from Bt stored [K][Ncols] (ldb = row stride) ----
            const int colL = tid & 127;
            const int kg = (tid >> 7) * 32;
            const unsigned short* g = Bt + (size_t)(k0 + kg) * ldb + bn + colL;
            unsigned short tmp[32];
#pragma unroll
            for (int i = 0; i < 32; ++i) tmp[i] = g[(size_t)i * ldb];
#pragma unroll
            for (int gg = 0; gg < 4; ++gg) {
                const int k8 = (kg >> 3) + gg;
                const int slot = k8 ^ (colL & 7);
                us8 v = { tmp[gg*8+0], tmp[gg*8+1], tmp[gg*8+2], tmp[gg*8+3],
                          tmp[gg*8+4], tmp[gg*8+5], tmp[gg*8+6], tmp[gg*8+7] };
                *(us8*)(BsB + colL * 128 + slot * 16) = v;
            }
        }
        __syncthreads();
#pragma unroll
        for (int kk = 0; kk < 2; ++kk) {
            s16x8 af[4], bf[4];
#pragma unroll
            for (int m = 0; m < 4; ++m) {
                const int row = wr * 64 + m * 16 + l15;
                const int slot = (kk * 4 + lq) ^ (row & 7);
                af[m] = *(const s16x8*)(AsB + row * 128 + slot * 16);
            }
#pragma unroll
            for (int n = 0; n < 4; ++n) {
                const int col = wc * 64 + n * 16 + l15;
                const int slot = (kk * 4 + lq) ^ (col & 7);
                bf[n] = *(const s16x8*)(BsB + col * 128 + slot * 16);
            }
#pragma unroll
            for (int m = 0; m < 4; ++m)
#pragma unroll
                for (int n = 0; n < 4; ++n)
                    acc[m][n] = __builtin_amdgcn_mfma_f32_16x16x32_bf16(
                        af[m], bf[n], acc[m][n], 0, 0, 0);
        }
        __syncthreads();
    }

    float* cf = Cf ? Cf + (size_t)z * sCfb : nullptr;
    unsigned short* cb = Cb ? Cb + (size_t)z * sCbb : nullptr;
#pragma unroll
    for (int m = 0; m < 4; ++m) {
#pragma unroll
        for (int n = 0; n < 4; ++n) {
            const int col = bn + wc * 64 + n * 16 + l15;
            f32x4 v = acc[m][n];
#pragma unroll
            for (int r = 0; r < 4; ++r) {
                const int gr = bm + wr * 64 + m * 16 + lq * 4 + r;
                if (gr >= M) continue;
                float o = v[r] * scale;
                if (EPI == 3) {
                    o += aux1[(size_t)gr * ldc + col] + aux2[(size_t)gr * ldc + col];
                    o = fmaxf(o, 0.f);
                }
                if (EPI == 4) o += aux1[col];
                if (cf) cf[(size_t)gr * ldc + col] = o;
                if (cb) cb[(size_t)gr * ldcb + col] = f2bf(o);
            }
        }
    }
}

// ---------------------------------------------------------------------------
// Bulk f32 -> bf16 convert (8 elems/thread)
// ---------------------------------------------------------------------------
__global__ __launch_bounds__(256)
void convert_bf16(const float* __restrict__ in, unsigned short* __restrict__ out, int n8)
{
    const int i = blockIdx.x * 256 + threadIdx.x;
    if (i >= n8) return;
    float4 a = ((const float4*)in)[i * 2];
    float4 b = ((const float4*)in)[i * 2 + 1];
    us8 o = { f2bf(a.x), f2bf(a.y), f2bf(a.z), f2bf(a.w),
              f2bf(b.x), f2bf(b.y), f2bf(b.z), f2bf(b.w) };
    ((us8*)out)[i] = o;
}

// ---------------------------------------------------------------------------
// Transpose + convert: in f32 [R][C] -> out bf16 [C][R]. Grid (C/64, R/64).
// ---------------------------------------------------------------------------
__global__ __launch_bounds__(256)
void conv_wT(const float* __restrict__ in, unsigned short* __restrict__ outT,
             int R, int C)
{
    __shared__ unsigned short t[64][65];
    const int c0 = blockIdx.x * 64, r0 = blockIdx.y * 64;
    const int r = threadIdx.x >> 4, cq = (threadIdx.x & 15) << 2;
#pragma unroll
    for (int i = 0; i < 4; ++i) {
        const int rr = r + i * 16;
        float4 v = *(const float4*)(in + (size_t)(r0 + rr) * C + c0 + cq);
        t[rr][cq + 0] = f2bf(v.x); t[rr][cq + 1] = f2bf(v.y);
        t[rr][cq + 2] = f2bf(v.z); t[rr][cq + 3] = f2bf(v.w);
    }
    __syncthreads();
    const int c = threadIdx.x >> 2, sq = (threadIdx.x & 3) << 4;
    us8 o0, o1;
#pragma unroll
    for (int i = 0; i < 8; ++i) { o0[i] = t[sq + i][c]; o1[i] = t[sq + 8 + i][c]; }
    *(us8*)(outT + (size_t)(c0 + c) * R + r0 + sq) = o0;
    *(us8*)(outT + (size_t)(c0 + c) * R + r0 + sq + 8) = o1;
}

// ---------------------------------------------------------------------------
// y0_bf = bf16(embeds[tgt_y])
// ---------------------------------------------------------------------------
__global__ __launch_bounds__(64)
void gather_embed(const float* __restrict__ embeds, const int* __restrict__ tgt_y,
                  unsigned short* __restrict__ yb)
{
    const int i = blockIdx.x, c = threadIdx.x << 2;
    const int v = tgt_y[i];
    float4 e = *(const float4*)(embeds + (size_t)v * 256 + c);
    us4 o = { f2bf(e.x), f2bf(e.y), f2bf(e.z), f2bf(e.w) };
    *(us4*)(yb + (size_t)i * 256 + c) = o;
}

// ---------------------------------------------------------------------------
// agg[tgt[e],:] += h[src[e],:] + Ee[etype[e],:]   (fp32 atomics)
// ---------------------------------------------------------------------------
__global__ __launch_bounds__(256)
void scatter_edges(const float* __restrict__ h, const float* __restrict__ Ee,
                   const int* __restrict__ src, const int* __restrict__ tgt,
                   const int* __restrict__ etype, float* __restrict__ agg)
{
    const int e = blockIdx.x;
    const int c = threadIdx.x;
    const int s = src[e], t = tgt[e], ty = etype[e];
    const float val = h[(size_t)s * 256 + c] + Ee[(size_t)ty * 256 + c];
    atomicAdd(&agg[(size_t)t * 256 + c], val);
}

// ---------------------------------------------------------------------------
// Row softmax over 256 entries (in place, f32) + bf16 copy.
// ---------------------------------------------------------------------------
__global__ __launch_bounds__(256)
void softmax_rows(float* __restrict__ L, unsigned short* __restrict__ Lb)
{
    const int wave = blockIdx.x * 4 + (threadIdx.x >> 6);
    const int lane = threadIdx.x & 63;
    float* row = L + (size_t)wave * 256;
    float4 v = *(const float4*)(row + (lane << 2));
    float m = fmaxf(fmaxf(v.x, v.y), fmaxf(v.z, v.w));
#pragma unroll
    for (int o = 32; o > 0; o >>= 1) m = fmaxf(m, __shfl_xor(m, o));
    v.x = __expf(v.x - m); v.y = __expf(v.y - m);
    v.z = __expf(v.z - m); v.w = __expf(v.w - m);
    float s = v.x + v.y + v.z + v.w;
#pragma unroll
    for (int o = 32; o > 0; o >>= 1) s += __shfl_xor(s, o);
    const float inv = 1.0f / s;
    v.x *= inv; v.y *= inv; v.z *= inv; v.w *= inv;
    *(float4*)(row + (lane << 2)) = v;
    us4 o = { f2bf(v.x), f2bf(v.y), f2bf(v.z), f2bf(v.w) };
    *(us4*)(Lb + (size_t)wave * 256 + (lane << 2)) = o;
}

// ---------------------------------------------------------------------------
// y_edge_rel_score[e,j] = concat(y[src[e]], y[tgt[e]]) . W[:,j] + b[j]
// ---------------------------------------------------------------------------
__global__ __launch_bounds__(256)
void edge_score(const float* __restrict__ y, const int* __restrict__ src,
                const int* __restrict__ tgt, const float* __restrict__ W,
                const float* __restrict__ bias, float* __restrict__ out)
{
    const int t = blockIdx.x * 256 + threadIdx.x;
    const int e = t >> 3, j = t & 7;
    if (e >= NE_) return;
    const float* ys = y + (size_t)src[e] * 256;
    const float* yt = y + (size_t)tgt[e] * 256;
    float acc = bias[j];
    for (int c = 0; c < 256; ++c) acc = fmaf(ys[c], W[c * 8 + j], acc);
    for (int c = 0; c < 256; ++c) acc = fmaf(yt[c], W[(256 + c) * 8 + j], acc);
    out[(size_t)e * 8 + j] = acc;
}

// ---------------------------------------------------------------------------
extern "C" void kernel_launch(void* const* d_in, const int* in_sizes, int n_in,
                              void* d_out, int out_size, void* d_ws, size_t ws_size,
                              hipStream_t stream)
{
    const float* x       = (const float*)d_in[0];
    const int*   tgt_y   = (const int*)d_in[2];
    const int*   eidx    = (const int*)d_in[3];
    const int*   etype   = (const int*)d_in[4];
    const float* embeds  = (const float*)d_in[6];
    const float* W_in[3] = {(const float*)d_in[7],  (const float*)d_in[11], (const float*)d_in[15]};
    const float* Wq[3]   = {(const float*)d_in[8],  (const float*)d_in[12], (const float*)d_in[16]};
    const float* Wv[3]   = {(const float*)d_in[9],  (const float*)d_in[13], (const float*)d_in[17]};
    const float* Ee[3]   = {(const float*)d_in[10], (const float*)d_in[14], (const float*)d_in[18]};
    const float* lin_z_w = (const float*)d_in[19];
    const float* lin_z_b = (const float*)d_in[20];
    const float* lin_g_w = (const float*)d_in[21];
    const float* lin_g_b = (const float*)d_in[22];
    const int* src = eidx;
    const int* tgt = eidx + NE_;

    float* out = (float*)d_out;
    // d_out layout (floats)
    float* y_final = out;                        // [17920][256]
    float* score   = out + 4587520;              // [17920][256]
    float* esc     = out + 9175040;              // [71680][8]
    float* aout[3] = {out + 9748480, out + 14336000, out + 18923520}; // [B][70][256]

    // workspace layout (bytes)
    char* wsb = (char*)d_ws;
    unsigned short* xb   = (unsigned short*)(wsb + 0);            // [B][256][512]  67,108,864
    float*          h    = (float*)         (wsb + 67108864);     // [17920][256]   18,350,080
    unsigned short* hb   = (unsigned short*)(wsb + 85458944);     // h_bf / alpha_bf 9,175,040
    float*          agg  = (float*)         (wsb + 94633984);     // [17920][256]   18,350,080
    unsigned short* qb   = (unsigned short*)(wsb + 112984064);    // q_bf / ctxF_bf 18,350,080
    unsigned short* yb   = (unsigned short*)(wsb + 131334144);    // y_bf            9,175,040
    char* wt = wsb + 140509184;                                   // transposed weights
    unsigned short* winT[3], *wqT[3], *wvT[3];
    for (int l = 0; l < 3; ++l) {
        winT[l] = (unsigned short*)(wt + l * 131072);
        wqT[l]  = (unsigned short*)(wt + 393216  + l * 262144);
        wvT[l]  = (unsigned short*)(wt + 1179648 + l * 262144);
    }
    unsigned short* lzT = (unsigned short*)(wt + 1966080);

    // --- one-time conversions ---
    // x has B*SX*F = 33,554,432 floats -> n8 = 4,194,304 (us8 elements)
    convert_bf16<<<16384, 256, 0, stream>>>(x, xb, 4194304);
    for (int l = 0; l < 3; ++l) {
        conv_wT<<<dim3(4, 4), 256, 0, stream>>>(W_in[l], winT[l], 256, 256);
        conv_wT<<<dim3(8, 4), 256, 0, stream>>>(Wq[l],   wqT[l],  256, 512);
        conv_wT<<<dim3(4, 8), 256, 0, stream>>>(Wv[l],   wvT[l],  512, 256);
    }
    conv_wT<<<dim3(4, 4), 256, 0, stream>>>(lin_z_w, lzT, 256, 256);
    gather_embed<<<NY_, 64, 0, stream>>>(embeds, tgt_y, yb);

    const float qscale = 0.044194173824159216f;  // 1/sqrt(512)
    for (int l = 0; l < 3; ++l) {
        // h = y @ W_in  (f32 + bf16)
        gemm_mfma<0,0><<<dim3(2, 140, 1), 256, 0, stream>>>(
            yb, 256, 0,  winT[l], 256, 0,
            h, 256, 0,   hb, 256, 0,
            nullptr, nullptr, NY_, 256, 1.f);
        // agg = segment_sum(h[src] + Ee[etype], tgt)
        hipMemsetAsync(agg, 0, (size_t)NY_ * 256 * sizeof(float), stream);
        scatter_edges<<<NE_, 256, 0, stream>>>(h, Ee[l], src, tgt, etype, agg);
        // q_bf = h @ Wq
        gemm_mfma<0,0><<<dim3(4, 140, 1), 256, 0, stream>>>(
            hb, 256, 0,  wqT[l], 256, 0,
            nullptr, 0, 0,  qb, 512, 0,
            nullptr, nullptr, NY_, 256, 1.f);
        // logits = scale * q @ x^T  (per batch) -> d_out alpha region (f32)
        gemm_mfma<0,0><<<dim3(2, 1, B_), 256, 0, stream>>>(
            qb, 512, (long)SY_ * F_,  xb, 512, (long)SX_ * F_,
            aout[l], 256, (long)SY_ * SX_,  nullptr, 0, 0,
            nullptr, nullptr, SY_, 512, qscale);
        // softmax in place + bf16 copy
        softmax_rows<<<4480, 256, 0, stream>>>(aout[l], hb);
        // ctxF_bf = alpha @ x_b   (B staged transposed from [K][N] layout)
        gemm_mfma<0,1><<<dim3(4, 1, B_), 256, 0, stream>>>(
            hb, 256, (long)SY_ * SX_,  xb, 512, (long)SX_ * F_,
            nullptr, 0, 0,  qb, 512, (long)SY_ * F_,
            nullptr, nullptr, SY_, 256, 1.f);
        // y_next = relu(h + agg + ctxF @ Wv)  (f32 only on last layer, bf16 always)
        gemm_mfma<3,0><<<dim3(2, 140, 1), 256, 0, stream>>>(
            qb, 512, 0,  wvT[l], 512, 0,
            (l == 2) ? y_final : nullptr, 256, 0,  yb, 256, 0,
            h, agg, NY_, 512, 1.f);
    }
    // y_score = y @ lin_z_w + lin_z_b
    gemm_mfma<4,0><<<dim3(2, 140, 1), 256, 0, stream>>>(
        yb, 256, 0,  lzT, 256, 0,
        score, 256, 0,  nullptr, 0, 0,
        lin_z_b, nullptr, NY_, 256, 1.f);
    // edge relation scores
    edge_score<<<2240, 256, 0, stream>>>(y_final, src, tgt, lin_g_w, lin_g_b, esc);
}

// Round 4
// 599.025 us; speedup vs baseline: 2.6343x; 1.1912x over previous
//
#include <hip/hip_runtime.h>
#include <cstddef>
#include <cstdint>

#define B_    256
#define SX_   256
#define SY_   70
#define F_    512
#define EMB_  256
#define NY_   (B_*SY_)     // 17920
#define NE_   (4*B_*SY_)   // 71680

typedef short s16x8 __attribute__((ext_vector_type(8)));   // MFMA A/B frag (8 bf16)
typedef float f32x4 __attribute__((ext_vector_type(4)));   // MFMA C/D frag
typedef unsigned short us4 __attribute__((ext_vector_type(4)));
typedef unsigned short us8 __attribute__((ext_vector_type(8)));

__device__ __forceinline__ unsigned short f2bf(float f) {
    unsigned u = __builtin_bit_cast(unsigned, f);
    u += 0x7fffu + ((u >> 16) & 1u);          // RNE
    return (unsigned short)(u >> 16);
}

// ---------------------------------------------------------------------------
// Unified bf16 MFMA GEMM, C = A @ Bt^T. A:[M][K] bf16, Bt:[N][K] bf16.
// 128x128 tile, BK=64, 4 waves (2x2 of 64x64), 16x16x32 MFMA.
// EPI: 0 = plain; 3 = relu(acc+aux1+aux2); 4 = acc + aux1[col] (bias)
// ---------------------------------------------------------------------------
template<int EPI, int TB>
__global__ __launch_bounds__(256, 2)
void gemm_mfma(const unsigned short* __restrict__ A, int lda, long sAb,
               const unsigned short* __restrict__ Bt, int ldb, long sBb,
               float* __restrict__ Cf, int ldc, long sCfb,
               unsigned short* __restrict__ Cb, int ldcb, long sCbb,
               const float* __restrict__ aux1, const float* __restrict__ aux2,
               int M, int K, float scale)
{
    __shared__ unsigned short As[128 * 64];
    __shared__ unsigned short Bs[128 * 64];
    char* AsB = (char*)As;
    char* BsB = (char*)Bs;
    const int tid = threadIdx.x;
    const int z = blockIdx.z;
    A  += (size_t)z * sAb;
    Bt += (size_t)z * sBb;
    const int bm = blockIdx.y * 128, bn = blockIdx.x * 128;
    const int lane = tid & 63;
    const int w = tid >> 6, wr = w >> 1, wc = w & 1;
    const int l15 = lane & 15, lq = lane >> 4;

    f32x4 acc[4][4];
    const f32x4 z4 = {0.f, 0.f, 0.f, 0.f};
#pragma unroll
    for (int m = 0; m < 4; ++m)
#pragma unroll
        for (int n = 0; n < 4; ++n) acc[m][n] = z4;

    for (int k0 = 0; k0 < K; k0 += 64) {
        // ---- stage A tile [128 rows][64 k] ----
#pragma unroll
        for (int i = 0; i < 4; ++i) {
            const int row = i * 32 + (tid >> 3);
            const int k8  = (tid & 7) ^ (row & 7);
            int ra = bm + row; ra = (ra < M) ? ra : (M - 1);
            const unsigned short* g = A + (size_t)ra * lda + k0 + k8 * 8;
            __builtin_amdgcn_global_load_lds(
                (const __attribute__((address_space(1))) unsigned int*)g,
                (__attribute__((address_space(3))) unsigned int*)(AsB + i * 4096 + tid * 16),
                16, 0, 0);
        }
        if (TB == 0) {
            // ---- stage B tile [128 cols][64 k] from Bt[N][K] ----
#pragma unroll
            for (int i = 0; i < 4; ++i) {
                const int row = i * 32 + (tid >> 3);
                const int k8  = (tid & 7) ^ (row & 7);
                const unsigned short* g = Bt + (size_t)(bn + row) * ldb + k0 + k8 * 8;
                __builtin_amdgcn_global_load_lds(
                    (const __attribute__((address_space(1))) unsigned int*)g,
                    (__attribute__((address_space(3))) unsigned int*)(BsB + i * 4096 + tid * 16),
                    16, 0, 0);
            }
        } else {
            // ---- stage B tile from Bt stored [K][Ncols] (ldb = row stride) ----
            const int colL = tid & 127;
            const int kg = (tid >> 7) * 32;
            const unsigned short* g = Bt + (size_t)(k0 + kg) * ldb + bn + colL;
            unsigned short tmp[32];
#pragma unroll
            for (int i = 0; i < 32; ++i) tmp[i] = g[(size_t)i * ldb];
#pragma unroll
            for (int gg = 0; gg < 4; ++gg) {
                const int k8 = (kg >> 3) + gg;
                const int slot = k8 ^ (colL & 7);
                us8 v = { tmp[gg*8+0], tmp[gg*8+1], tmp[gg*8+2], tmp[gg*8+3],
                          tmp[gg*8+4], tmp[gg*8+5], tmp[gg*8+6], tmp[gg*8+7] };
                *(us8*)(BsB + colL * 128 + slot * 16) = v;
            }
        }
        __syncthreads();
#pragma unroll
        for (int kk = 0; kk < 2; ++kk) {
            s16x8 af[4], bf[4];
#pragma unroll
            for (int m = 0; m < 4; ++m) {
                const int row = wr * 64 + m * 16 + l15;
                const int slot = (kk * 4 + lq) ^ (row & 7);
                af[m] = *(const s16x8*)(AsB + row * 128 + slot * 16);
            }
#pragma unroll
            for (int n = 0; n < 4; ++n) {
                const int col = wc * 64 + n * 16 + l15;
                const int slot = (kk * 4 + lq) ^ (col & 7);
                bf[n] = *(const s16x8*)(BsB + col * 128 + slot * 16);
            }
#pragma unroll
            for (int m = 0; m < 4; ++m)
#pragma unroll
                for (int n = 0; n < 4; ++n)
                    acc[m][n] = __builtin_amdgcn_mfma_f32_16x16x32_bf16(
                        af[m], bf[n], acc[m][n], 0, 0, 0);
        }
        __syncthreads();
    }

    float* cf = Cf ? Cf + (size_t)z * sCfb : nullptr;
    unsigned short* cb = Cb ? Cb + (size_t)z * sCbb : nullptr;
#pragma unroll
    for (int m = 0; m < 4; ++m) {
#pragma unroll
        for (int n = 0; n < 4; ++n) {
            const int col = bn + wc * 64 + n * 16 + l15;
            f32x4 v = acc[m][n];
#pragma unroll
            for (int r = 0; r < 4; ++r) {
                const int gr = bm + wr * 64 + m * 16 + lq * 4 + r;
                if (gr >= M) continue;
                float o = v[r] * scale;
                if (EPI == 3) {
                    o += aux1[(size_t)gr * ldc + col] + aux2[(size_t)gr * ldc + col];
                    o = fmaxf(o, 0.f);
                }
                if (EPI == 4) o += aux1[col];
                if (cf) cf[(size_t)gr * ldc + col] = o;
                if (cb) cb[(size_t)gr * ldcb + col] = f2bf(o);
            }
        }
    }
}

// ---------------------------------------------------------------------------
__global__ __launch_bounds__(256)
void convert_bf16(const float* __restrict__ in, unsigned short* __restrict__ out, int n8)
{
    const int i = blockIdx.x * 256 + threadIdx.x;
    if (i >= n8) return;
    float4 a = ((const float4*)in)[i * 2];
    float4 b = ((const float4*)in)[i * 2 + 1];
    us8 o = { f2bf(a.x), f2bf(a.y), f2bf(a.z), f2bf(a.w),
              f2bf(b.x), f2bf(b.y), f2bf(b.z), f2bf(b.w) };
    ((us8*)out)[i] = o;
}

// ---------------------------------------------------------------------------
// Transpose + convert: in f32 [R][C] -> out bf16 [C][R]. Grid (C/64, R/64).
// ---------------------------------------------------------------------------
__global__ __launch_bounds__(256)
void conv_wT(const float* __restrict__ in, unsigned short* __restrict__ outT,
             int R, int C)
{
    __shared__ unsigned short t[64][65];
    const int c0 = blockIdx.x * 64, r0 = blockIdx.y * 64;
    const int r = threadIdx.x >> 4, cq = (threadIdx.x & 15) << 2;
#pragma unroll
    for (int i = 0; i < 4; ++i) {
        const int rr = r + i * 16;
        float4 v = *(const float4*)(in + (size_t)(r0 + rr) * C + c0 + cq);
        t[rr][cq + 0] = f2bf(v.x); t[rr][cq + 1] = f2bf(v.y);
        t[rr][cq + 2] = f2bf(v.z); t[rr][cq + 3] = f2bf(v.w);
    }
    __syncthreads();
    const int c = threadIdx.x >> 2, sq = (threadIdx.x & 3) << 4;
    us8 o0, o1;
#pragma unroll
    for (int i = 0; i < 8; ++i) { o0[i] = t[sq + i][c]; o1[i] = t[sq + 8 + i][c]; }
    *(us8*)(outT + (size_t)(c0 + c) * R + r0 + sq) = o0;
    *(us8*)(outT + (size_t)(c0 + c) * R + r0 + sq + 8) = o1;
}

// ---------------------------------------------------------------------------
__global__ __launch_bounds__(64)
void gather_embed(const float* __restrict__ embeds, const int* __restrict__ tgt_y,
                  unsigned short* __restrict__ yb)
{
    const int i = blockIdx.x, c = threadIdx.x << 2;
    const int v = tgt_y[i];
    float4 e = *(const float4*)(embeds + (size_t)v * 256 + c);
    us4 o = { f2bf(e.x), f2bf(e.y), f2bf(e.z), f2bf(e.w) };
    *(us4*)(yb + (size_t)i * 256 + c) = o;
}

// ---------------------------------------------------------------------------
// CSR build: deg -> exclusive scan -> bucket fill  (edge index is layer-invariant)
// ---------------------------------------------------------------------------
__global__ __launch_bounds__(256)
void edge_deg(const int* __restrict__ tgt, int* __restrict__ deg)
{
    const int e = blockIdx.x * 256 + threadIdx.x;
    if (e < NE_) atomicAdd(&deg[tgt[e]], 1);
}

__global__ __launch_bounds__(1024)
void scan_off(const int* __restrict__ deg, int* __restrict__ off, int* __restrict__ cursor)
{
    __shared__ int ls[1024];
    const int t = threadIdx.x;
    const int base = t * 18;
    int local[18];
    int s = 0;
#pragma unroll
    for (int i = 0; i < 18; ++i) {
        const int idx = base + i;
        const int v = (idx < NY_) ? deg[idx] : 0;
        local[i] = s; s += v;
    }
    ls[t] = s;
    __syncthreads();
    for (int d = 1; d < 1024; d <<= 1) {
        int v = (t >= d) ? ls[t - d] : 0;
        __syncthreads();
        ls[t] += v;
        __syncthreads();
    }
    const int excl = (t == 0) ? 0 : ls[t - 1];
#pragma unroll
    for (int i = 0; i < 18; ++i) {
        const int idx = base + i;
        if (idx < NY_) {
            const int o = excl + local[i];
            off[idx] = o; cursor[idx] = o;
        }
    }
    if (t == 1023) off[NY_] = ls[1023];
}

__global__ __launch_bounds__(256)
void edge_fill(const int* __restrict__ tgt, int* __restrict__ cursor,
               int* __restrict__ elist)
{
    const int e = blockIdx.x * 256 + threadIdx.x;
    if (e >= NE_) return;
    const int pos = atomicAdd(&cursor[tgt[e]], 1);
    elist[pos] = e;
}

// ---------------------------------------------------------------------------
// agg[t,:] = sum_{e in bucket(t)} h[src[e],:] + cnt_type * Ee[type,:]
// One block per target node; no atomics, each output written once.
// ---------------------------------------------------------------------------
__global__ __launch_bounds__(256)
void node_agg(const float* __restrict__ h, const float* __restrict__ Ee,
              const int* __restrict__ src, const int* __restrict__ etype,
              const int* __restrict__ off, const int* __restrict__ elist,
              float* __restrict__ agg)
{
    const int t = blockIdx.x, c = threadIdx.x;
    const int k0 = off[t], k1 = off[t + 1];
    float s = 0.f;
    int cnt0 = 0, cnt1 = 0, cnt2 = 0, cnt3 = 0;
    for (int k = k0; k < k1; ++k) {
        const int e = elist[k];
        s += h[(size_t)src[e] * 256 + c];
        const int ty = etype[e];
        cnt0 += (ty == 0); cnt1 += (ty == 1); cnt2 += (ty == 2); cnt3 += (ty == 3);
    }
    s += cnt0 * Ee[c] + cnt1 * Ee[256 + c] + cnt2 * Ee[512 + c] + cnt3 * Ee[768 + c];
    agg[(size_t)t * 256 + c] = s;
}

// ---------------------------------------------------------------------------
// Row softmax over 256 entries (in place, f32) + bf16 copy.
// ---------------------------------------------------------------------------
__global__ __launch_bounds__(256)
void softmax_rows(float* __restrict__ L, unsigned short* __restrict__ Lb)
{
    const int wave = blockIdx.x * 4 + (threadIdx.x >> 6);
    const int lane = threadIdx.x & 63;
    float* row = L + (size_t)wave * 256;
    float4 v = *(const float4*)(row + (lane << 2));
    float m = fmaxf(fmaxf(v.x, v.y), fmaxf(v.z, v.w));
#pragma unroll
    for (int o = 32; o > 0; o >>= 1) m = fmaxf(m, __shfl_xor(m, o));
    v.x = __expf(v.x - m); v.y = __expf(v.y - m);
    v.z = __expf(v.z - m); v.w = __expf(v.w - m);
    float s = v.x + v.y + v.z + v.w;
#pragma unroll
    for (int o = 32; o > 0; o >>= 1) s += __shfl_xor(s, o);
    const float inv = 1.0f / s;
    v.x *= inv; v.y *= inv; v.z *= inv; v.w *= inv;
    *(float4*)(row + (lane << 2)) = v;
    us4 o = { f2bf(v.x), f2bf(v.y), f2bf(v.z), f2bf(v.w) };
    *(us4*)(Lb + (size_t)wave * 256 + (lane << 2)) = o;
}

// ---------------------------------------------------------------------------
// Y12[i][0:8]  = y[i] @ lin_g_w[0:256],  Y12[i][8:16] = y[i] @ lin_g_w[256:512]
// Block = 16 rows; W (512x8) and y-rows staged in LDS.
// ---------------------------------------------------------------------------
__global__ __launch_bounds__(256)
void edge_w(const float* __restrict__ y, const float* __restrict__ W,
            float* __restrict__ Y12)
{
    __shared__ float Ws[4096];       // 512 x 8
    __shared__ float ys[16][260];
    const int tid = threadIdx.x;
#pragma unroll
    for (int i = 0; i < 4; ++i)
        ((float4*)Ws)[i * 256 + tid] = ((const float4*)W)[i * 256 + tid];
    const int r = tid >> 4, seg = tid & 15;
    const int r0 = blockIdx.x * 16;
#pragma unroll
    for (int i = 0; i < 4; ++i) {
        const int c4 = seg + i * 16;
        *(float4*)&ys[r][c4 * 4] = *(const float4*)(y + (size_t)(r0 + r) * 256 + c4 * 4);
    }
    __syncthreads();
    const int j = tid & 15;
    const int row = tid >> 4;
    const float* Wcol = Ws + ((j < 8) ? j : (2048 + j - 8));
    float acc = 0.f;
#pragma unroll 4
    for (int c = 0; c < 256; ++c) acc = fmaf(ys[row][c], Wcol[c * 8], acc);
    Y12[(size_t)(r0 + row) * 16 + j] = acc;
}

// ---------------------------------------------------------------------------
// esc[e,0:8] = Y12[src[e],0:8] + Y12[tgt[e],8:16] + b
// ---------------------------------------------------------------------------
__global__ __launch_bounds__(256)
void edge_gather(const float* __restrict__ Y12, const int* __restrict__ src,
                 const int* __restrict__ tgt, const float* __restrict__ bias,
                 float* __restrict__ esc)
{
    const int e = blockIdx.x * 256 + threadIdx.x;
    if (e >= NE_) return;
    const float* a = Y12 + (size_t)src[e] * 16;
    const float* b = Y12 + (size_t)tgt[e] * 16 + 8;
    float4 a0 = ((const float4*)a)[0], a1 = ((const float4*)a)[1];
    float4 b0 = ((const float4*)b)[0], b1 = ((const float4*)b)[1];
    float4 c0 = ((const float4*)bias)[0], c1 = ((const float4*)bias)[1];
    float4 o0, o1;
    o0.x = a0.x + b0.x + c0.x; o0.y = a0.y + b0.y + c0.y;
    o0.z = a0.z + b0.z + c0.z; o0.w = a0.w + b0.w + c0.w;
    o1.x = a1.x + b1.x + c1.x; o1.y = a1.y + b1.y + c1.y;
    o1.z = a1.z + b1.z + c1.z; o1.w = a1.w + b1.w + c1.w;
    ((float4*)(esc + (size_t)e * 8))[0] = o0;
    ((float4*)(esc + (size_t)e * 8))[1] = o1;
}

// ---------------------------------------------------------------------------
extern "C" void kernel_launch(void* const* d_in, const int* in_sizes, int n_in,
                              void* d_out, int out_size, void* d_ws, size_t ws_size,
                              hipStream_t stream)
{
    const float* x       = (const float*)d_in[0];
    const int*   tgt_y   = (const int*)d_in[2];
    const int*   eidx    = (const int*)d_in[3];
    const int*   etype   = (const int*)d_in[4];
    const float* embeds  = (const float*)d_in[6];
    const float* W_in[3] = {(const float*)d_in[7],  (const float*)d_in[11], (const float*)d_in[15]};
    const float* Wq[3]   = {(const float*)d_in[8],  (const float*)d_in[12], (const float*)d_in[16]};
    const float* Wv[3]   = {(const float*)d_in[9],  (const float*)d_in[13], (const float*)d_in[17]};
    const float* Ee[3]   = {(const float*)d_in[10], (const float*)d_in[14], (const float*)d_in[18]};
    const float* lin_z_w = (const float*)d_in[19];
    const float* lin_z_b = (const float*)d_in[20];
    const float* lin_g_w = (const float*)d_in[21];
    const float* lin_g_b = (const float*)d_in[22];
    const int* src = eidx;
    const int* tgt = eidx + NE_;

    float* out = (float*)d_out;
    // d_out layout (floats)
    float* y_final = out;                        // [17920][256]
    float* score   = out + 4587520;              // [17920][256]
    float* esc     = out + 9175040;              // [71680][8]
    float* aout[3] = {out + 9748480, out + 14336000, out + 18923520}; // [B][70][256]

    // workspace layout (bytes)
    char* wsb = (char*)d_ws;
    unsigned short* xb   = (unsigned short*)(wsb + 0);            // 67,108,864
    float*          h    = (float*)         (wsb + 67108864);     // 18,350,080
    unsigned short* hb   = (unsigned short*)(wsb + 85458944);     //  9,175,040
    float*          agg  = (float*)         (wsb + 94633984);     // 18,350,080
    unsigned short* qb   = (unsigned short*)(wsb + 112984064);    // 18,350,080
    unsigned short* yb   = (unsigned short*)(wsb + 131334144);    //  9,175,040
    char* wt = wsb + 140509184;                                   // weights, 2,097,152
    unsigned short* winT[3], *wqT[3], *wvT[3];
    for (int l = 0; l < 3; ++l) {
        winT[l] = (unsigned short*)(wt + l * 131072);
        wqT[l]  = (unsigned short*)(wt + 393216  + l * 262144);
        wvT[l]  = (unsigned short*)(wt + 1179648 + l * 262144);
    }
    unsigned short* lzT = (unsigned short*)(wt + 1966080);
    char* extra = wsb + 142606336;
    float* Y12    = (float*)extra;                 // 1,146,880
    int*   deg    = (int*)(extra + 1146880);       //    71,680
    int*   off    = (int*)(extra + 1218560);       //    71,684
    int*   cursor = (int*)(extra + 1290244);       //    71,680
    int*   elist  = (int*)(extra + 1361924);       //   286,720  (end ~144.3 MB)

    // --- CSR build (edge index is layer-invariant) ---
    hipMemsetAsync(deg, 0, NY_ * sizeof(int), stream);
    edge_deg<<<280, 256, 0, stream>>>(tgt, deg);
    scan_off<<<1, 1024, 0, stream>>>(deg, off, cursor);
    edge_fill<<<280, 256, 0, stream>>>(tgt, cursor, elist);

    // --- one-time conversions ---
    convert_bf16<<<16384, 256, 0, stream>>>(x, xb, 4194304);   // 33.55M floats
    for (int l = 0; l < 3; ++l) {
        conv_wT<<<dim3(4, 4), 256, 0, stream>>>(W_in[l], winT[l], 256, 256);
        conv_wT<<<dim3(8, 4), 256, 0, stream>>>(Wq[l],   wqT[l],  256, 512);
        conv_wT<<<dim3(4, 8), 256, 0, stream>>>(Wv[l],   wvT[l],  512, 256);
    }
    conv_wT<<<dim3(4, 4), 256, 0, stream>>>(lin_z_w, lzT, 256, 256);
    gather_embed<<<NY_, 64, 0, stream>>>(embeds, tgt_y, yb);

    const float qscale = 0.044194173824159216f;  // 1/sqrt(512)
    for (int l = 0; l < 3; ++l) {
        // h = y @ W_in  (f32 + bf16)
        gemm_mfma<0,0><<<dim3(2, 140, 1), 256, 0, stream>>>(
            yb, 256, 0,  winT[l], 256, 0,
            h, 256, 0,   hb, 256, 0,
            nullptr, nullptr, NY_, 256, 1.f);
        // agg = segment_sum(h[src] + Ee[etype], tgt)  — CSR, no atomics
        node_agg<<<NY_, 256, 0, stream>>>(h, Ee[l], src, etype, off, elist, agg);
        // q_bf = h @ Wq
        gemm_mfma<0,0><<<dim3(4, 140, 1), 256, 0, stream>>>(
            hb, 256, 0,  wqT[l], 256, 0,
            nullptr, 0, 0,  qb, 512, 0,
            nullptr, nullptr, NY_, 256, 1.f);
        // logits = scale * q @ x^T  (per batch) -> d_out alpha region (f32)
        gemm_mfma<0,0><<<dim3(2, 1, B_), 256, 0, stream>>>(
            qb, 512, (long)SY_ * F_,  xb, 512, (long)SX_ * F_,
            aout[l], 256, (long)SY_ * SX_,  nullptr, 0, 0,
            nullptr, nullptr, SY_, 512, qscale);
        // softmax in place + bf16 copy
        softmax_rows<<<4480, 256, 0, stream>>>(aout[l], hb);
        // ctxF_bf = alpha @ x_b   (B staged transposed from [K][N] layout)
        gemm_mfma<0,1><<<dim3(4, 1, B_), 256, 0, stream>>>(
            hb, 256, (long)SY_ * SX_,  xb, 512, (long)SX_ * F_,
            nullptr, 0, 0,  qb, 512, (long)SY_ * F_,
            nullptr, nullptr, SY_, 256, 1.f);
        // y_next = relu(h + agg + ctxF @ Wv)
        gemm_mfma<3,0><<<dim3(2, 140, 1), 256, 0, stream>>>(
            qb, 512, 0,  wvT[l], 512, 0,
            (l == 2) ? y_final : nullptr, 256, 0,  yb, 256, 0,
            h, agg, NY_, 512, 1.f);
    }
    // y_score = y @ lin_z_w + lin_z_b
    gemm_mfma<4,0><<<dim3(2, 140, 1), 256, 0, stream>>>(
        yb, 256, 0,  lzT, 256, 0,
        score, 256, 0,  nullptr, 0, 0,
        lin_z_b, nullptr, NY_, 256, 1.f);
    // edge relation scores: Y12 projection + gather-add
    edge_w<<<1120, 256, 0, stream>>>(y_final, lin_g_w, Y12);
    edge_gather<<<280, 256, 0, stream>>>(Y12, src, tgt, lin_g_b, esc);
}